// Round 1
// baseline (216.582 us; speedup 1.0000x reference)
//
#include <hip/hip_runtime.h>
#include <hip/hip_bf16.h>

typedef __attribute__((ext_vector_type(8))) short bf16x8;
typedef __attribute__((ext_vector_type(4))) float f32x4;

#define DEVINL __device__ __forceinline__

constexpr int kB = 8, kL = 512, kDH = 768, kDARC = 512, kDREL = 128, kC = 37;
constexpr int kBL = kB * kL;        // 4096
constexpr int kNP = 1280;           // 512+512+128+128 fused projection cols
constexpr int kNY = kC * kDREL;     // 4736

constexpr long nHB   = (long)kBL * kDH;          // 3,145,728
constexpr long nWALL = (long)kNP * kDH;          //   983,040
constexpr long nWARC = (long)kDARC * kDARC;      //   262,144
constexpr long nUT   = (long)kC * kDREL * kDREL; //   606,208
constexpr long nBALL = kNP;

DEVINL short f2b(float f) {
  unsigned u = __float_as_uint(f);
  u += 0x7fffu + ((u >> 16) & 1u);   // RNE
  return (short)(u >> 16);
}
DEVINL float b2f(short s) {
  return __uint_as_float(((unsigned)(unsigned short)s) << 16);
}

// ---------------- convert / pack inputs to bf16 ----------------
__global__ __launch_bounds__(256) void k_convert(
    const float* __restrict__ H, const float* __restrict__ W_ah, const float* __restrict__ b_ah,
    const float* __restrict__ W_ad, const float* __restrict__ b_ad,
    const float* __restrict__ W_arc, const float* __restrict__ W_rh, const float* __restrict__ b_rh,
    const float* __restrict__ W_rd, const float* __restrict__ b_rd, const float* __restrict__ U,
    short* __restrict__ Hb, short* __restrict__ Wall, float* __restrict__ ballf,
    short* __restrict__ Warcb, short* __restrict__ Ut)
{
  const long total = nHB + nWALL + nWARC + nUT + nBALL;
  for (long i = (long)blockIdx.x * blockDim.x + threadIdx.x; i < total;
       i += (long)gridDim.x * blockDim.x) {
    if (i < nHB) {
      Hb[i] = f2b(H[i]);
    } else if (i < nHB + nWALL) {
      long j = i - nHB; int row = (int)(j / kDH); int k = (int)(j - (long)row * kDH);
      float v;
      if (row < 512)       v = W_ah[(long)row * kDH + k];
      else if (row < 1024) v = W_ad[(long)(row - 512) * kDH + k];
      else if (row < 1152) v = W_rh[(long)(row - 1024) * kDH + k];
      else                 v = W_rd[(long)(row - 1152) * kDH + k];
      Wall[j] = f2b(v);
    } else if (i < nHB + nWALL + nWARC) {
      long j = i - nHB - nWALL;
      Warcb[j] = f2b(W_arc[j]);
    } else if (i < nHB + nWALL + nWARC + nUT) {
      long j = i - nHB - nWALL - nWARC;
      int c = (int)(j >> 14); int rem = (int)(j & 16383); int e = rem >> 7; int d = rem & 127;
      Ut[j] = f2b(U[(long)c * 16384 + (long)d * 128 + e]);   // Ut[c][e][d] = U[c][d][e]
    } else {
      int n = (int)(i - nHB - nWALL - nWARC - nUT);
      float v;
      if (n < 512)       v = b_ah[n];
      else if (n < 1024) v = b_ad[n - 512];
      else if (n < 1152) v = b_rh[n - 1024];
      else               v = b_rd[n - 1152];
      ballf[n] = v;
    }
  }
}

// ---------------- generic 64x64 MFMA tile core: C += A[64,K] * B[64,K]^T ----------------
// A,B row-major bf16(short). bValid = number of valid B rows in this tile (rest -> 0).
DEVINL void gemm_core(const short* __restrict__ A, long lda,
                      const short* __restrict__ Bm, long ldb,
                      int K, int bValid, f32x4 acc[2][2])
{
  __shared__ short As[64 * 40];   // +8 bf16 pad per row -> 2-way-max bank conflicts
  __shared__ short Bs[64 * 40];
  const int t = threadIdx.x;
  const int lane = t & 63;
  const int w = t >> 6;
  const int wm = w >> 1, wn = w & 1;
  const int lrow = t >> 2;          // 0..63
  const int lcol = (t & 3) * 8;     // 0,8,16,24
  const int fr = lane & 15, hi = lane >> 4;

  for (int k0 = 0; k0 < K; k0 += 32) {
    bf16x8 av = *(const bf16x8*)(A + (long)lrow * lda + k0 + lcol);
    bf16x8 bv = {0, 0, 0, 0, 0, 0, 0, 0};
    if (lrow < bValid) bv = *(const bf16x8*)(Bm + (long)lrow * ldb + k0 + lcol);
    __syncthreads();   // previous iteration's fragment reads drained
    *(bf16x8*)&As[lrow * 40 + lcol] = av;
    *(bf16x8*)&Bs[lrow * 40 + lcol] = bv;
    __syncthreads();
    // k-contiguous fragment fill: same k-bijection for A and B => correct for any HW k-map
    bf16x8 a0 = *(const bf16x8*)&As[(32 * wm + fr) * 40 + hi * 8];
    bf16x8 a1 = *(const bf16x8*)&As[(32 * wm + 16 + fr) * 40 + hi * 8];
    bf16x8 b0 = *(const bf16x8*)&Bs[(32 * wn + fr) * 40 + hi * 8];
    bf16x8 b1 = *(const bf16x8*)&Bs[(32 * wn + 16 + fr) * 40 + hi * 8];
    acc[0][0] = __builtin_amdgcn_mfma_f32_16x16x32_bf16(a0, b0, acc[0][0], 0, 0, 0);
    acc[0][1] = __builtin_amdgcn_mfma_f32_16x16x32_bf16(a0, b1, acc[0][1], 0, 0, 0);
    acc[1][0] = __builtin_amdgcn_mfma_f32_16x16x32_bf16(a1, b0, acc[1][0], 0, 0, 0);
    acc[1][1] = __builtin_amdgcn_mfma_f32_16x16x32_bf16(a1, b1, acc[1][1], 0, 0, 0);
  }
}

#define EPI_SETUP \
  const int lane = threadIdx.x & 63; const int w = threadIdx.x >> 6; \
  const int wm = w >> 1, wn = w & 1, fr = lane & 15, hi = lane >> 4;

#define ZERO_ACC \
  f32x4 acc[2][2]; \
  for (int i = 0; i < 2; i++) for (int j = 0; j < 2; j++) for (int r = 0; r < 4; r++) acc[i][j][r] = 0.f;

// ---------------- projections: Proj = relu(Hb * Wall^T + ballf), bf16 out ----------------
__global__ __launch_bounds__(256) void k_proj(const short* __restrict__ Hb,
    const short* __restrict__ Wall, const float* __restrict__ ballf,
    short* __restrict__ Proj)
{
  const int tn = blockIdx.x, tm = blockIdx.y;
  ZERO_ACC;
  gemm_core(Hb + (long)tm * 64 * kDH, kDH, Wall + (long)tn * 64 * kDH, kDH, kDH, 64, acc);
  EPI_SETUP;
  for (int i = 0; i < 2; i++) for (int j = 0; j < 2; j++) for (int r = 0; r < 4; r++) {
    int row = tm * 64 + 32 * wm + 16 * i + hi * 4 + r;
    int col = tn * 64 + 32 * wn + 16 * j + fr;
    float v = acc[i][j][r] + ballf[col];
    v = v > 0.f ? v : 0.f;
    Proj[(long)row * kNP + col] = f2b(v);
  }
}

// ---------------- T = Had * W_arc^T (bf16 out) ----------------
__global__ __launch_bounds__(256) void k_T(const short* __restrict__ Proj,
    const short* __restrict__ Warcb, short* __restrict__ T)
{
  const int tn = blockIdx.x, tm = blockIdx.y;
  ZERO_ACC;
  gemm_core(Proj + (long)tm * 64 * kNP + 512, kNP,
            Warcb + (long)tn * 64 * kDARC, kDARC, kDARC, 64, acc);
  EPI_SETUP;
  for (int i = 0; i < 2; i++) for (int j = 0; j < 2; j++) for (int r = 0; r < 4; r++) {
    int row = tm * 64 + 32 * wm + 16 * i + hi * 4 + r;
    int col = tn * 64 + 32 * wn + 16 * j + fr;
    T[(long)row * kDARC + col] = f2b(acc[i][j][r]);
  }
}

// ---------------- rowterm[bl] = Hah[bl,:] . bias_arc ----------------
__global__ __launch_bounds__(64) void k_rowterm(const short* __restrict__ Proj,
    const float* __restrict__ bias_arc, float* __restrict__ rowterm)
{
  const int bl = blockIdx.x; const int lane = threadIdx.x;
  const short* row = Proj + (long)bl * kNP;            // Hah = cols 0..511
  bf16x8 hv = *(const bf16x8*)(row + lane * 8);
  float s = 0.f;
  for (int i = 0; i < 8; i++) s += b2f(hv[i]) * bias_arc[lane * 8 + i];
  for (int off = 32; off > 0; off >>= 1) s += __shfl_down(s, off, 64);
  if (lane == 0) rowterm[bl] = s;
}

// ---------------- affB[bl,c] = concat(Hrh,Hrd)[bl] . W_rel[c] + bias_rel[c] ----------------
__global__ __launch_bounds__(64) void k_affine(const short* __restrict__ Proj,
    const float* __restrict__ W_rel, const float* __restrict__ bias_rel,
    float* __restrict__ affB)
{
  const int bl = blockIdx.x; const int lane = threadIdx.x;
  __shared__ float h[256];
  const short* row = Proj + (long)bl * kNP + 1024;     // Hrh|Hrd contiguous cols 1024..1279
  if (lane < 32) {
    bf16x8 v = *(const bf16x8*)(row + lane * 8);
    for (int i = 0; i < 8; i++) h[lane * 8 + i] = b2f(v[i]);
  }
  __syncthreads();
  if (lane < kC) {
    float s = bias_rel[lane];
    const float* wr = W_rel + (long)lane * 256;
    for (int k = 0; k < 256; k++) s += h[k] * wr[k];
    affB[(long)bl * kC + lane] = s;
  }
}

// ---------------- Y = Hrh * Ut^T (bf16 out), Y[bl][(c,e)] ----------------
__global__ __launch_bounds__(256) void k_Y(const short* __restrict__ Proj,
    const short* __restrict__ Ut, short* __restrict__ Y)
{
  const int tn = blockIdx.x, tm = blockIdx.y;
  ZERO_ACC;
  gemm_core(Proj + (long)tm * 64 * kNP + 1024, kNP,
            Ut + (long)tn * 64 * kDREL, kDREL, kDREL, 64, acc);
  EPI_SETUP;
  for (int i = 0; i < 2; i++) for (int j = 0; j < 2; j++) for (int r = 0; r < 4; r++) {
    int row = tm * 64 + 32 * wm + 16 * i + hi * 4 + r;
    int col = tn * 64 + 32 * wn + 16 * j + fr;
    Y[(long)row * kNY + col] = f2b(acc[i][j][r]);
  }
}

// ---------------- S_arc[b,l,m] = T_b[l] . Hah_b[m] + rowterm[b,l] ----------------
__global__ __launch_bounds__(256) void k_sarc(const short* __restrict__ T,
    const short* __restrict__ Proj, const float* __restrict__ rowterm,
    float* __restrict__ out)
{
  const int tn = blockIdx.x, tm = blockIdx.y, b = blockIdx.z;
  ZERO_ACC;
  gemm_core(T + ((long)b * kL + tm * 64) * kDARC, kDARC,
            Proj + ((long)b * kL + tn * 64) * kNP, kNP, kDARC, 64, acc);
  EPI_SETUP;
  for (int i = 0; i < 2; i++) for (int j = 0; j < 2; j++) for (int r = 0; r < 4; r++) {
    int l = tm * 64 + 32 * wm + 16 * i + hi * 4 + r;
    int m = tn * 64 + 32 * wn + 16 * j + fr;
    out[((long)b * kL + l) * kL + m] = acc[i][j][r] + rowterm[(long)b * kL + l];
  }
}

// ---------------- S_rel[b,l,m,c] = Hrd_b[m] . Y_bl[c] + affB[bl,c] ----------------
__global__ __launch_bounds__(256) void k_srel(const short* __restrict__ Proj,
    const short* __restrict__ Y, const float* __restrict__ affB,
    float* __restrict__ out2)
{
  const int tm = blockIdx.y; const int bl = blockIdx.z;
  const int b = bl >> 9;
  ZERO_ACC;
  gemm_core(Proj + ((long)b * kL + tm * 64) * kNP + 1152, kNP,
            Y + (long)bl * kNY, kDREL, kDREL, kC, acc);
  EPI_SETUP;
  for (int i = 0; i < 2; i++) for (int j = 0; j < 2; j++) for (int r = 0; r < 4; r++) {
    int m = tm * 64 + 32 * wm + 16 * i + hi * 4 + r;
    int c = 32 * wn + 16 * j + fr;
    if (c < kC)
      out2[((long)bl * kL + m) * kC + c] = acc[i][j][r] + affB[(long)bl * kC + c];
  }
}

extern "C" void kernel_launch(void* const* d_in, const int* in_sizes, int n_in,
                              void* d_out, int out_size, void* d_ws, size_t ws_size,
                              hipStream_t stream) {
  const float* H        = (const float*)d_in[0];
  const float* W_ah     = (const float*)d_in[1];
  const float* b_ah     = (const float*)d_in[2];
  const float* W_ad     = (const float*)d_in[3];
  const float* b_ad     = (const float*)d_in[4];
  const float* W_arc    = (const float*)d_in[5];
  const float* bias_arc = (const float*)d_in[6];
  const float* W_rh     = (const float*)d_in[7];
  const float* b_rh     = (const float*)d_in[8];
  const float* W_rd     = (const float*)d_in[9];
  const float* b_rd     = (const float*)d_in[10];
  const float* U_rel    = (const float*)d_in[11];
  const float* W_rel    = (const float*)d_in[12];
  const float* bias_rel = (const float*)d_in[13];

  size_t off = 0;
  auto take = [&](size_t nbytes) -> void* {
    void* p = (char*)d_ws + off;
    off += (nbytes + 255) & ~(size_t)255;
    return p;
  };
  short* Hb      = (short*)take(nHB * 2);
  short* Wall    = (short*)take(nWALL * 2);
  float* ballf   = (float*)take(nBALL * 4);
  short* Warcb   = (short*)take(nWARC * 2);
  short* Ut      = (short*)take(nUT * 2);
  short* Proj    = (short*)take((long)kBL * kNP * 2);
  short* T       = (short*)take((long)kBL * kDARC * 2);
  short* Y       = (short*)take((long)kBL * kNY * 2);
  float* rowterm = (float*)take((long)kBL * 4);
  float* affB    = (float*)take((long)kBL * kC * 4);
  if (off > ws_size) return;   // insufficient workspace -> fail loudly in validation

  float* outArc = (float*)d_out;
  float* outRel = outArc + (long)kB * kL * kL;

  k_convert<<<dim3(4096), dim3(256), 0, stream>>>(H, W_ah, b_ah, W_ad, b_ad, W_arc,
                                                  W_rh, b_rh, W_rd, b_rd, U_rel,
                                                  Hb, Wall, ballf, Warcb, Ut);
  k_proj<<<dim3(kNP / 64, kBL / 64), dim3(256), 0, stream>>>(Hb, Wall, ballf, Proj);
  k_rowterm<<<dim3(kBL), dim3(64), 0, stream>>>(Proj, bias_arc, rowterm);
  k_affine<<<dim3(kBL), dim3(64), 0, stream>>>(Proj, W_rel, bias_rel, affB);
  k_T<<<dim3(kDARC / 64, kBL / 64), dim3(256), 0, stream>>>(Proj, Warcb, T);
  k_Y<<<dim3(kNY / 64, kBL / 64), dim3(256), 0, stream>>>(Proj, Ut, Y);
  k_sarc<<<dim3(kL / 64, kL / 64, kB), dim3(256), 0, stream>>>(T, Proj, rowterm, outArc);
  k_srel<<<dim3(1, kL / 64, kBL), dim3(256), 0, stream>>>(Proj, Y, affB, outRel);
}

// Round 2
// 201.804 us; speedup vs baseline: 1.0732x; 1.0732x over previous
//
#include <hip/hip_runtime.h>
#include <hip/hip_bf16.h>

typedef __attribute__((ext_vector_type(8))) short bf16x8;
typedef __attribute__((ext_vector_type(4))) float f32x4;

#define DEVINL __device__ __forceinline__

constexpr int kB = 8, kL = 512, kDH = 768, kDARC = 512, kDREL = 128, kC = 37;
constexpr int kBL = kB * kL;        // 4096
constexpr int kNP = 1280;           // 512+512+128+128 fused projection cols
constexpr int kNY = kC * kDREL;     // 4736

constexpr long nHB   = (long)kBL * kDH;          // 3,145,728
constexpr long nWALL = (long)kNP * kDH;          //   983,040
constexpr long nWARC = (long)kDARC * kDARC;      //   262,144
constexpr long nUT   = (long)kC * kDREL * kDREL; //   606,208
constexpr long nBALL = kNP;

DEVINL short f2b(float f) {
  unsigned u = __float_as_uint(f);
  u += 0x7fffu + ((u >> 16) & 1u);   // RNE
  return (short)(u >> 16);
}
DEVINL float b2f(short s) {
  return __uint_as_float(((unsigned)(unsigned short)s) << 16);
}

// ---------------- convert / pack inputs to bf16 ----------------
__global__ __launch_bounds__(256) void k_convert(
    const float* __restrict__ H, const float* __restrict__ W_ah, const float* __restrict__ b_ah,
    const float* __restrict__ W_ad, const float* __restrict__ b_ad,
    const float* __restrict__ W_arc, const float* __restrict__ W_rh, const float* __restrict__ b_rh,
    const float* __restrict__ W_rd, const float* __restrict__ b_rd, const float* __restrict__ U,
    short* __restrict__ Hb, short* __restrict__ Wall, float* __restrict__ ballf,
    short* __restrict__ Warcb, short* __restrict__ Ut)
{
  const long total = nHB + nWALL + nWARC + nUT + nBALL;
  for (long i = (long)blockIdx.x * blockDim.x + threadIdx.x; i < total;
       i += (long)gridDim.x * blockDim.x) {
    if (i < nHB) {
      Hb[i] = f2b(H[i]);
    } else if (i < nHB + nWALL) {
      long j = i - nHB; int row = (int)(j / kDH); int k = (int)(j - (long)row * kDH);
      float v;
      if (row < 512)       v = W_ah[(long)row * kDH + k];
      else if (row < 1024) v = W_ad[(long)(row - 512) * kDH + k];
      else if (row < 1152) v = W_rh[(long)(row - 1024) * kDH + k];
      else                 v = W_rd[(long)(row - 1152) * kDH + k];
      Wall[j] = f2b(v);
    } else if (i < nHB + nWALL + nWARC) {
      long j = i - nHB - nWALL;
      Warcb[j] = f2b(W_arc[j]);
    } else if (i < nHB + nWALL + nWARC + nUT) {
      long j = i - nHB - nWALL - nWARC;
      int c = (int)(j >> 14); int rem = (int)(j & 16383); int e = rem >> 7; int d = rem & 127;
      Ut[j] = f2b(U[(long)c * 16384 + (long)d * 128 + e]);   // Ut[c][e][d] = U[c][d][e]
    } else {
      int n = (int)(i - nHB - nWALL - nWARC - nUT);
      float v;
      if (n < 512)       v = b_ah[n];
      else if (n < 1024) v = b_ad[n - 512];
      else if (n < 1152) v = b_rh[n - 1024];
      else               v = b_rd[n - 1152];
      ballf[n] = v;
    }
  }
}

// ---------------- generic 64x64 MFMA tile core: C += A[64,K] * B[64,K]^T ----------------
DEVINL void gemm_core(const short* __restrict__ A, long lda,
                      const short* __restrict__ Bm, long ldb,
                      int K, int bValid, f32x4 acc[2][2])
{
  __shared__ short As[64 * 40];
  __shared__ short Bs[64 * 40];
  const int t = threadIdx.x;
  const int lane = t & 63;
  const int w = t >> 6;
  const int wm = w >> 1, wn = w & 1;
  const int lrow = t >> 2;
  const int lcol = (t & 3) * 8;
  const int fr = lane & 15, hi = lane >> 4;

  for (int k0 = 0; k0 < K; k0 += 32) {
    bf16x8 av = *(const bf16x8*)(A + (long)lrow * lda + k0 + lcol);
    bf16x8 bv = {0, 0, 0, 0, 0, 0, 0, 0};
    if (lrow < bValid) bv = *(const bf16x8*)(Bm + (long)lrow * ldb + k0 + lcol);
    __syncthreads();
    *(bf16x8*)&As[lrow * 40 + lcol] = av;
    *(bf16x8*)&Bs[lrow * 40 + lcol] = bv;
    __syncthreads();
    bf16x8 a0 = *(const bf16x8*)&As[(32 * wm + fr) * 40 + hi * 8];
    bf16x8 a1 = *(const bf16x8*)&As[(32 * wm + 16 + fr) * 40 + hi * 8];
    bf16x8 b0 = *(const bf16x8*)&Bs[(32 * wn + fr) * 40 + hi * 8];
    bf16x8 b1 = *(const bf16x8*)&Bs[(32 * wn + 16 + fr) * 40 + hi * 8];
    acc[0][0] = __builtin_amdgcn_mfma_f32_16x16x32_bf16(a0, b0, acc[0][0], 0, 0, 0);
    acc[0][1] = __builtin_amdgcn_mfma_f32_16x16x32_bf16(a0, b1, acc[0][1], 0, 0, 0);
    acc[1][0] = __builtin_amdgcn_mfma_f32_16x16x32_bf16(a1, b0, acc[1][0], 0, 0, 0);
    acc[1][1] = __builtin_amdgcn_mfma_f32_16x16x32_bf16(a1, b1, acc[1][1], 0, 0, 0);
  }
}

#define EPI_SETUP \
  const int lane = threadIdx.x & 63; const int w = threadIdx.x >> 6; \
  const int wm = w >> 1, wn = w & 1, fr = lane & 15, hi = lane >> 4;

#define ZERO_ACC \
  f32x4 acc[2][2]; \
  for (int i = 0; i < 2; i++) for (int j = 0; j < 2; j++) for (int r = 0; r < 4; r++) acc[i][j][r] = 0.f;

// ---------------- projections: Proj = relu(Hb * Wall^T + ballf), bf16 out ----------------
__global__ __launch_bounds__(256) void k_proj(const short* __restrict__ Hb,
    const short* __restrict__ Wall, const float* __restrict__ ballf,
    short* __restrict__ Proj)
{
  const int tn = blockIdx.x, tm = blockIdx.y;
  ZERO_ACC;
  gemm_core(Hb + (long)tm * 64 * kDH, kDH, Wall + (long)tn * 64 * kDH, kDH, kDH, 64, acc);
  EPI_SETUP;
  for (int i = 0; i < 2; i++) for (int j = 0; j < 2; j++) for (int r = 0; r < 4; r++) {
    int row = tm * 64 + 32 * wm + 16 * i + hi * 4 + r;
    int col = tn * 64 + 32 * wn + 16 * j + fr;
    float v = acc[i][j][r] + ballf[col];
    v = v > 0.f ? v : 0.f;
    Proj[(long)row * kNP + col] = f2b(v);
  }
}

// ---------------- T = Had * W_arc^T (bf16 out) ----------------
__global__ __launch_bounds__(256) void k_T(const short* __restrict__ Proj,
    const short* __restrict__ Warcb, short* __restrict__ T)
{
  const int tn = blockIdx.x, tm = blockIdx.y;
  ZERO_ACC;
  gemm_core(Proj + (long)tm * 64 * kNP + 512, kNP,
            Warcb + (long)tn * 64 * kDARC, kDARC, kDARC, 64, acc);
  EPI_SETUP;
  for (int i = 0; i < 2; i++) for (int j = 0; j < 2; j++) for (int r = 0; r < 4; r++) {
    int row = tm * 64 + 32 * wm + 16 * i + hi * 4 + r;
    int col = tn * 64 + 32 * wn + 16 * j + fr;
    T[(long)row * kDARC + col] = f2b(acc[i][j][r]);
  }
}

// ---------------- rowterm[bl] = Hah[bl,:] . bias_arc ----------------
__global__ __launch_bounds__(64) void k_rowterm(const short* __restrict__ Proj,
    const float* __restrict__ bias_arc, float* __restrict__ rowterm)
{
  const int bl = blockIdx.x; const int lane = threadIdx.x;
  const short* row = Proj + (long)bl * kNP;
  bf16x8 hv = *(const bf16x8*)(row + lane * 8);
  float s = 0.f;
  for (int i = 0; i < 8; i++) s += b2f(hv[i]) * bias_arc[lane * 8 + i];
  for (int off = 32; off > 0; off >>= 1) s += __shfl_down(s, off, 64);
  if (lane == 0) rowterm[bl] = s;
}

// ---------------- affB[bl,c] = concat(Hrh,Hrd)[bl] . W_rel[c] + bias_rel[c] ----------------
__global__ __launch_bounds__(64) void k_affine(const short* __restrict__ Proj,
    const float* __restrict__ W_rel, const float* __restrict__ bias_rel,
    float* __restrict__ affB)
{
  const int bl = blockIdx.x; const int lane = threadIdx.x;
  __shared__ float h[256];
  const short* row = Proj + (long)bl * kNP + 1024;
  if (lane < 32) {
    bf16x8 v = *(const bf16x8*)(row + lane * 8);
    for (int i = 0; i < 8; i++) h[lane * 8 + i] = b2f(v[i]);
  }
  __syncthreads();
  if (lane < kC) {
    float s = bias_rel[lane];
    const float* wr = W_rel + (long)lane * 256;
    for (int k = 0; k < 256; k++) s += h[k] * wr[k];
    affB[(long)bl * kC + lane] = s;
  }
}

// ---------------- Y = Hrh * Ut^T (bf16 out), Y[bl][(c,e)] ----------------
__global__ __launch_bounds__(256) void k_Y(const short* __restrict__ Proj,
    const short* __restrict__ Ut, short* __restrict__ Y)
{
  const int tn = blockIdx.x, tm = blockIdx.y;
  ZERO_ACC;
  gemm_core(Proj + (long)tm * 64 * kNP + 1024, kNP,
            Ut + (long)tn * 64 * kDREL, kDREL, kDREL, 64, acc);
  EPI_SETUP;
  for (int i = 0; i < 2; i++) for (int j = 0; j < 2; j++) for (int r = 0; r < 4; r++) {
    int row = tm * 64 + 32 * wm + 16 * i + hi * 4 + r;
    int col = tn * 64 + 32 * wn + 16 * j + fr;
    Y[(long)row * kNY + col] = f2b(acc[i][j][r]);
  }
}

// ---------------- S_arc[b,l,m] = T_b[l] . Hah_b[m] + rowterm[b,l] ----------------
__global__ __launch_bounds__(256) void k_sarc(const short* __restrict__ T,
    const short* __restrict__ Proj, const float* __restrict__ rowterm,
    float* __restrict__ out)
{
  const int tn = blockIdx.x, tm = blockIdx.y, b = blockIdx.z;
  ZERO_ACC;
  gemm_core(T + ((long)b * kL + tm * 64) * kDARC, kDARC,
            Proj + ((long)b * kL + tn * 64) * kNP, kNP, kDARC, 64, acc);
  EPI_SETUP;
  for (int i = 0; i < 2; i++) for (int j = 0; j < 2; j++) for (int r = 0; r < 4; r++) {
    int l = tm * 64 + 32 * wm + 16 * i + hi * 4 + r;
    int m = tn * 64 + 32 * wn + 16 * j + fr;
    out[((long)b * kL + l) * kL + m] = acc[i][j][r] + rowterm[(long)b * kL + l];
  }
}

// ---------------- S_rel: A-resident restructure ----------------
// Block: 512 threads = 8 waves; wave w owns m rows [w*64, w*64+64).
// Grid: (64 l-chunks of 8, 8 batches). Hrd A-fragments live in registers
// across the whole l-chunk; per l only Y_bl (37x128 -> pad 48) is staged in LDS.
__global__ __launch_bounds__(512) void k_srel2(const short* __restrict__ Proj,
    const short* __restrict__ Y, const float* __restrict__ affB,
    float* __restrict__ out2)
{
  __shared__ short Bs[48 * 136];   // stride 136: bank-start 4*(fr+hi) mod 32, balanced
  const int t = threadIdx.x;
  const int lane = t & 63;
  const int w = t >> 6;
  const int fr = lane & 15, hi = lane >> 4;
  const int b = blockIdx.y;
  const int l0 = blockIdx.x * 8;

  // zero the pad rows 37..47 once (never overwritten)
  if (t < 176) {
    int c = 37 + (t >> 4), e = (t & 15) * 8;
    bf16x8 z = {0, 0, 0, 0, 0, 0, 0, 0};
    *(bf16x8*)&Bs[c * 136 + e] = z;
  }

  // A fragments: Hrd rows b*512 + w*64 + mf*16 + fr, k = ks*32 + hi*8 (Proj cols 1152+)
  bf16x8 a[4][4];
  const short* Ab = Proj + ((long)b * kL + w * 64) * kNP + 1152;
  for (int mf = 0; mf < 4; mf++)
    for (int ks = 0; ks < 4; ks++)
      a[mf][ks] = *(const bf16x8*)(Ab + (long)(mf * 16 + fr) * kNP + ks * 32 + hi * 8);

  for (int il = 0; il < 8; il++) {
    const long bl = (long)b * kL + l0 + il;
    const short* Yrow = Y + bl * kNY;
    __syncthreads();                       // prior iteration's Bs reads done
    for (int i = t; i < 592; i += 512) {   // 4736 bf16 = 592 x bf16x8
      int idx = i * 8, c = idx >> 7, e = idx & 127;
      *(bf16x8*)&Bs[c * 136 + e] = *(const bf16x8*)(Yrow + idx);
    }
    __syncthreads();

    f32x4 acc[4][3];
    for (int mf = 0; mf < 4; mf++) for (int nf = 0; nf < 3; nf++)
      for (int r = 0; r < 4; r++) acc[mf][nf][r] = 0.f;

    for (int ks = 0; ks < 4; ks++) {
      bf16x8 bfr[3];
      for (int nf = 0; nf < 3; nf++)
        bfr[nf] = *(const bf16x8*)&Bs[(nf * 16 + fr) * 136 + ks * 32 + hi * 8];
      for (int mf = 0; mf < 4; mf++)
        for (int nf = 0; nf < 3; nf++)
          acc[mf][nf] = __builtin_amdgcn_mfma_f32_16x16x32_bf16(a[mf][ks], bfr[nf], acc[mf][nf], 0, 0, 0);
    }

    float* ob = out2 + (bl * kL + w * 64) * kC;
    const float* afb = affB + bl * kC;
    for (int nf = 0; nf < 3; nf++) {
      int c = nf * 16 + fr;
      if (c < kC) {
        float aff = afb[c];
        for (int mf = 0; mf < 4; mf++)
          for (int r = 0; r < 4; r++)
            ob[(long)(mf * 16 + hi * 4 + r) * kC + c] = acc[mf][nf][r] + aff;
      }
    }
  }
}

extern "C" void kernel_launch(void* const* d_in, const int* in_sizes, int n_in,
                              void* d_out, int out_size, void* d_ws, size_t ws_size,
                              hipStream_t stream) {
  const float* H        = (const float*)d_in[0];
  const float* W_ah     = (const float*)d_in[1];
  const float* b_ah     = (const float*)d_in[2];
  const float* W_ad     = (const float*)d_in[3];
  const float* b_ad     = (const float*)d_in[4];
  const float* W_arc    = (const float*)d_in[5];
  const float* bias_arc = (const float*)d_in[6];
  const float* W_rh     = (const float*)d_in[7];
  const float* b_rh     = (const float*)d_in[8];
  const float* W_rd     = (const float*)d_in[9];
  const float* b_rd     = (const float*)d_in[10];
  const float* U_rel    = (const float*)d_in[11];
  const float* W_rel    = (const float*)d_in[12];
  const float* bias_rel = (const float*)d_in[13];

  size_t off = 0;
  auto take = [&](size_t nbytes) -> void* {
    void* p = (char*)d_ws + off;
    off += (nbytes + 255) & ~(size_t)255;
    return p;
  };
  short* Hb      = (short*)take(nHB * 2);
  short* Wall    = (short*)take(nWALL * 2);
  float* ballf   = (float*)take(nBALL * 4);
  short* Warcb   = (short*)take(nWARC * 2);
  short* Ut      = (short*)take(nUT * 2);
  short* Proj    = (short*)take((long)kBL * kNP * 2);
  short* T       = (short*)take((long)kBL * kDARC * 2);
  short* Y       = (short*)take((long)kBL * kNY * 2);
  float* rowterm = (float*)take((long)kBL * 4);
  float* affB    = (float*)take((long)kBL * kC * 4);
  if (off > ws_size) return;

  float* outArc = (float*)d_out;
  float* outRel = outArc + (long)kB * kL * kL;

  k_convert<<<dim3(4096), dim3(256), 0, stream>>>(H, W_ah, b_ah, W_ad, b_ad, W_arc,
                                                  W_rh, b_rh, W_rd, b_rd, U_rel,
                                                  Hb, Wall, ballf, Warcb, Ut);
  k_proj<<<dim3(kNP / 64, kBL / 64), dim3(256), 0, stream>>>(Hb, Wall, ballf, Proj);
  k_rowterm<<<dim3(kBL), dim3(64), 0, stream>>>(Proj, bias_arc, rowterm);
  k_affine<<<dim3(kBL), dim3(64), 0, stream>>>(Proj, W_rel, bias_rel, affB);
  k_T<<<dim3(kDARC / 64, kBL / 64), dim3(256), 0, stream>>>(Proj, Warcb, T);
  k_Y<<<dim3(kNY / 64, kBL / 64), dim3(256), 0, stream>>>(Proj, Ut, Y);
  k_sarc<<<dim3(kL / 64, kL / 64, kB), dim3(256), 0, stream>>>(T, Proj, rowterm, outArc);
  k_srel2<<<dim3(kL / 8, kB), dim3(512), 0, stream>>>(Proj, Y, affB, outRel);
}

// Round 3
// 200.740 us; speedup vs baseline: 1.0789x; 1.0053x over previous
//
#include <hip/hip_runtime.h>
#include <hip/hip_bf16.h>

typedef __attribute__((ext_vector_type(8))) short bf16x8;
typedef __attribute__((ext_vector_type(4))) float f32x4;

#define DEVINL __device__ __forceinline__

constexpr int kB = 8, kL = 512, kDH = 768, kDARC = 512, kDREL = 128, kC = 37;
constexpr int kBL = kB * kL;        // 4096
constexpr int kNP = 1280;           // 512+512+128+128 fused projection cols
constexpr int kNY = kC * kDREL;     // 4736

constexpr long nHB   = (long)kBL * kDH;
constexpr long nWALL = (long)kNP * kDH;
constexpr long nWARC = (long)kDARC * kDARC;
constexpr long nUT   = (long)kC * kDREL * kDREL;
constexpr long nBALL = kNP;

DEVINL short f2b(float f) {
  unsigned u = __float_as_uint(f);
  u += 0x7fffu + ((u >> 16) & 1u);   // RNE
  return (short)(u >> 16);
}
DEVINL float b2f(short s) {
  return __uint_as_float(((unsigned)(unsigned short)s) << 16);
}

// async global->LDS, 16B per lane. LDS dest = wave-uniform base + lane*16 (HW).
DEVINL void gload16(const void* g, void* l) {
  __builtin_amdgcn_global_load_lds(
      (const __attribute__((address_space(1))) void*)g,
      (__attribute__((address_space(3))) void*)l, 16, 0, 0);
}

// ---------------- convert / pack inputs to bf16 ----------------
__global__ __launch_bounds__(256) void k_convert(
    const float* __restrict__ H, const float* __restrict__ W_ah, const float* __restrict__ b_ah,
    const float* __restrict__ W_ad, const float* __restrict__ b_ad,
    const float* __restrict__ W_arc, const float* __restrict__ W_rh, const float* __restrict__ b_rh,
    const float* __restrict__ W_rd, const float* __restrict__ b_rd, const float* __restrict__ U,
    short* __restrict__ Hb, short* __restrict__ Wall, float* __restrict__ ballf,
    short* __restrict__ Warcb, short* __restrict__ Ut)
{
  const long total = nHB + nWALL + nWARC + nUT + nBALL;
  for (long i = (long)blockIdx.x * blockDim.x + threadIdx.x; i < total;
       i += (long)gridDim.x * blockDim.x) {
    if (i < nHB) {
      Hb[i] = f2b(H[i]);
    } else if (i < nHB + nWALL) {
      long j = i - nHB; int row = (int)(j / kDH); int k = (int)(j - (long)row * kDH);
      float v;
      if (row < 512)       v = W_ah[(long)row * kDH + k];
      else if (row < 1024) v = W_ad[(long)(row - 512) * kDH + k];
      else if (row < 1152) v = W_rh[(long)(row - 1024) * kDH + k];
      else                 v = W_rd[(long)(row - 1152) * kDH + k];
      Wall[j] = f2b(v);
    } else if (i < nHB + nWALL + nWARC) {
      long j = i - nHB - nWALL;
      Warcb[j] = f2b(W_arc[j]);
    } else if (i < nHB + nWALL + nWARC + nUT) {
      long j = i - nHB - nWALL - nWARC;
      int c = (int)(j >> 14); int rem = (int)(j & 16383); int e = rem >> 7; int d = rem & 127;
      Ut[j] = f2b(U[(long)c * 16384 + (long)d * 128 + e]);   // Ut[c][e][d] = U[c][d][e]
    } else {
      int n = (int)(i - nHB - nWALL - nWARC - nUT);
      float v;
      if (n < 512)       v = b_ah[n];
      else if (n < 1024) v = b_ad[n - 512];
      else if (n < 1152) v = b_rh[n - 1024];
      else               v = b_rd[n - 1152];
      ballf[n] = v;
    }
  }
}

// ---------------- 128x128 m97-style core: acc += A[128,K] * B[128,K]^T ----------------
// 256 threads / 4 waves; wave (wm,wn) owns the 64x64 quadrant. BK=64.
// Linear LDS [128][64], global_load_lds dwordx4 staging, 2 barriers per K-step.
DEVINL void gemm128_core(const short* __restrict__ Ag, long lda,
                         const short* __restrict__ Bg, long ldb,
                         int K, f32x4 acc[4][4])
{
  __shared__ short As[128 * 64];
  __shared__ short Bs[128 * 64];
  const int t = threadIdx.x, lane = t & 63, w = t >> 6;
  const int wm = w >> 1, wn = w & 1, fr = lane & 15, hi = lane >> 4;
  const int srow = w * 8 + (lane >> 3);     // staging row within 32-row slab
  const int scol = (lane & 7) * 8;          // staging col (shorts)
  const short* Arow = Ag + (long)srow * lda + scol;
  const short* Brow = Bg + (long)srow * ldb + scol;

  for (int k0 = 0; k0 < K; k0 += 64) {
    __syncthreads();                        // readers done with As/Bs
#pragma unroll
    for (int i = 0; i < 4; i++) {
      gload16(Arow + (long)i * 32 * lda + k0, &As[(i * 4 + w) * 512]);
      gload16(Brow + (long)i * 32 * ldb + k0, &Bs[(i * 4 + w) * 512]);
    }
    __syncthreads();                        // vmcnt(0) drained before barrier
#pragma unroll
    for (int ks = 0; ks < 2; ks++) {
      bf16x8 a[4], b[4];
#pragma unroll
      for (int mf = 0; mf < 4; mf++)
        a[mf] = *(const bf16x8*)&As[(wm * 64 + mf * 16 + fr) * 64 + ks * 32 + hi * 8];
#pragma unroll
      for (int nf = 0; nf < 4; nf++)
        b[nf] = *(const bf16x8*)&Bs[(wn * 64 + nf * 16 + fr) * 64 + ks * 32 + hi * 8];
#pragma unroll
      for (int mf = 0; mf < 4; mf++)
#pragma unroll
        for (int nf = 0; nf < 4; nf++)
          acc[mf][nf] = __builtin_amdgcn_mfma_f32_16x16x32_bf16(a[mf], b[nf], acc[mf][nf], 0, 0, 0);
    }
  }
}

#define EPI128_SETUP \
  const int lane = threadIdx.x & 63; const int w = threadIdx.x >> 6; \
  const int wm = w >> 1, wn = w & 1, fr = lane & 15, hi = lane >> 4;

#define ZERO_ACC16 \
  f32x4 acc[4][4]; \
  for (int i = 0; i < 4; i++) for (int j = 0; j < 4; j++) for (int r = 0; r < 4; r++) acc[i][j][r] = 0.f;

// ---------------- projections: Proj = relu(Hb * Wall^T + ballf), bf16 out ----------------
__global__ __launch_bounds__(256) void k_proj(const short* __restrict__ Hb,
    const short* __restrict__ Wall, const float* __restrict__ ballf,
    short* __restrict__ Proj)
{
  const int tn = blockIdx.x, tm = blockIdx.y;
  ZERO_ACC16;
  gemm128_core(Hb + (long)tm * 128 * kDH, kDH, Wall + (long)tn * 128 * kDH, kDH, kDH, acc);
  EPI128_SETUP;
  for (int mf = 0; mf < 4; mf++) for (int nf = 0; nf < 4; nf++) for (int r = 0; r < 4; r++) {
    int row = tm * 128 + wm * 64 + mf * 16 + hi * 4 + r;
    int col = tn * 128 + wn * 64 + nf * 16 + fr;
    float v = acc[mf][nf][r] + ballf[col];
    v = v > 0.f ? v : 0.f;
    Proj[(long)row * kNP + col] = f2b(v);
  }
}

// ---------------- T = Had * W_arc^T (bf16 out) ----------------
__global__ __launch_bounds__(256) void k_T(const short* __restrict__ Proj,
    const short* __restrict__ Warcb, short* __restrict__ T)
{
  const int tn = blockIdx.x, tm = blockIdx.y;
  ZERO_ACC16;
  gemm128_core(Proj + (long)tm * 128 * kNP + 512, kNP,
               Warcb + (long)tn * 128 * kDARC, kDARC, kDARC, acc);
  EPI128_SETUP;
  for (int mf = 0; mf < 4; mf++) for (int nf = 0; nf < 4; nf++) for (int r = 0; r < 4; r++) {
    int row = tm * 128 + wm * 64 + mf * 16 + hi * 4 + r;
    int col = tn * 128 + wn * 64 + nf * 16 + fr;
    T[(long)row * kDARC + col] = f2b(acc[mf][nf][r]);
  }
}

// ---------------- Y = Hrh * Ut^T (bf16 out), Y[bl][(c,e)] ----------------
__global__ __launch_bounds__(256) void k_Y(const short* __restrict__ Proj,
    const short* __restrict__ Ut, short* __restrict__ Y)
{
  const int tn = blockIdx.x, tm = blockIdx.y;
  ZERO_ACC16;
  gemm128_core(Proj + (long)tm * 128 * kNP + 1024, kNP,
               Ut + (long)tn * 128 * kDREL, kDREL, kDREL, acc);
  EPI128_SETUP;
  for (int mf = 0; mf < 4; mf++) for (int nf = 0; nf < 4; nf++) for (int r = 0; r < 4; r++) {
    int row = tm * 128 + wm * 64 + mf * 16 + hi * 4 + r;
    int col = tn * 128 + wn * 64 + nf * 16 + fr;
    Y[(long)row * kNY + col] = f2b(acc[mf][nf][r]);
  }
}

// ---------------- S_arc[b,l,m] = T_b[l] . Hah_b[m] + rowterm[b,l] ----------------
__global__ __launch_bounds__(256) void k_sarc(const short* __restrict__ T,
    const short* __restrict__ Proj, const float* __restrict__ rowterm,
    float* __restrict__ out)
{
  const int tn = blockIdx.x, tm = blockIdx.y, b = blockIdx.z;
  ZERO_ACC16;
  gemm128_core(T + ((long)b * kL + tm * 128) * kDARC, kDARC,
               Proj + ((long)b * kL + tn * 128) * kNP, kNP, kDARC, acc);
  EPI128_SETUP;
  for (int mf = 0; mf < 4; mf++) for (int nf = 0; nf < 4; nf++) for (int r = 0; r < 4; r++) {
    int l = tm * 128 + wm * 64 + mf * 16 + hi * 4 + r;
    int m = tn * 128 + wn * 64 + nf * 16 + fr;
    out[((long)b * kL + l) * kL + m] = acc[mf][nf][r] + rowterm[(long)b * kL + l];
  }
}

// ---------------- rowterm[bl] = Hah[bl,:] . bias_arc ----------------
__global__ __launch_bounds__(64) void k_rowterm(const short* __restrict__ Proj,
    const float* __restrict__ bias_arc, float* __restrict__ rowterm)
{
  const int bl = blockIdx.x; const int lane = threadIdx.x;
  const short* row = Proj + (long)bl * kNP;
  bf16x8 hv = *(const bf16x8*)(row + lane * 8);
  float s = 0.f;
  for (int i = 0; i < 8; i++) s += b2f(hv[i]) * bias_arc[lane * 8 + i];
  for (int off = 32; off > 0; off >>= 1) s += __shfl_down(s, off, 64);
  if (lane == 0) rowterm[bl] = s;
}

// ---------------- affB[bl,c] = concat(Hrh,Hrd)[bl] . W_rel[c] + bias_rel[c] ----------------
__global__ __launch_bounds__(64) void k_affine(const short* __restrict__ Proj,
    const float* __restrict__ W_rel, const float* __restrict__ bias_rel,
    float* __restrict__ affB)
{
  const int bl = blockIdx.x; const int lane = threadIdx.x;
  __shared__ float h[256];
  const short* row = Proj + (long)bl * kNP + 1024;
  if (lane < 32) {
    bf16x8 v = *(const bf16x8*)(row + lane * 8);
    for (int i = 0; i < 8; i++) h[lane * 8 + i] = b2f(v[i]);
  }
  __syncthreads();
  if (lane < kC) {
    float s = bias_rel[lane];
    const float* wr = W_rel + (long)lane * 256;
    for (int k = 0; k < 256; k++) s += h[k] * wr[k];
    affB[(long)bl * kC + lane] = s;
  }
}

// ---------------- S_rel: A-resident, double-buffered Y, 1 barrier/l ----------------
// 512 threads = 8 waves; wave w owns m rows [w*64, w*64+64). Grid: (64 l-chunks, 8 b).
__global__ __launch_bounds__(512) void k_srel2(const short* __restrict__ Proj,
    const short* __restrict__ Y, const float* __restrict__ affB,
    float* __restrict__ out2)
{
  __shared__ short Bs[2][48 * 136];   // stride 136: balanced bank starts for b128 reads
  const int t = threadIdx.x;
  const int lane = t & 63;
  const int w = t >> 6;
  const int fr = lane & 15, hi = lane >> 4;
  const int b = blockIdx.y;
  const int l0 = blockIdx.x * 8;

  // zero pad rows 37..47 of both buffers once (cols 0..127 only; tail never read)
  if (t < 352) {
    int buf = t / 176, q = t % 176;
    int c = 37 + (q >> 4), e = (q & 15) * 8;
    bf16x8 z = {0, 0, 0, 0, 0, 0, 0, 0};
    *(bf16x8*)&Bs[buf][c * 136 + e] = z;
  }

  // A fragments: Hrd rows b*512 + w*64 + mf*16 + fr, k = ks*32 + hi*8 (Proj cols 1152+)
  bf16x8 a[4][4];
  const short* Ab = Proj + ((long)b * kL + w * 64) * kNP + 1152;
#pragma unroll
  for (int mf = 0; mf < 4; mf++)
#pragma unroll
    for (int ks = 0; ks < 4; ks++)
      a[mf][ks] = *(const bf16x8*)(Ab + (long)(mf * 16 + fr) * kNP + ks * 32 + hi * 8);

  // prologue: stage l0 into buf 0 (chunk t -> row t>>4, col (t&15)*8; chunks 512+t for t<80)
  {
    const short* Yrow = Y + ((long)b * kL + l0) * kNY;
    bf16x8 s0 = *(const bf16x8*)(Yrow + t * 8);
    *(bf16x8*)&Bs[0][(t >> 4) * 136 + (t & 15) * 8] = s0;
    if (t < 80) {
      int c2 = 512 + t;
      bf16x8 s1 = *(const bf16x8*)(Yrow + (long)c2 * 8);
      *(bf16x8*)&Bs[0][(c2 >> 4) * 136 + (c2 & 15) * 8] = s1;
    }
  }
  __syncthreads();

  int cur = 0;
  for (int il = 0; il < 8; il++) {
    const long bl = (long)b * kL + l0 + il;

    // T14: issue next-l global loads before compute
    bf16x8 n0, n1;
    if (il < 7) {
      const short* Yn = Y + (bl + 1) * kNY;
      n0 = *(const bf16x8*)(Yn + t * 8);
      if (t < 80) n1 = *(const bf16x8*)(Yn + (long)(512 + t) * 8);
    }

    f32x4 acc[4][3];
#pragma unroll
    for (int mf = 0; mf < 4; mf++)
#pragma unroll
      for (int nf = 0; nf < 3; nf++)
        for (int r = 0; r < 4; r++) acc[mf][nf][r] = 0.f;

#pragma unroll
    for (int ks = 0; ks < 4; ks++) {
      bf16x8 bfr[3];
#pragma unroll
      for (int nf = 0; nf < 3; nf++)
        bfr[nf] = *(const bf16x8*)&Bs[cur][(nf * 16 + fr) * 136 + ks * 32 + hi * 8];
#pragma unroll
      for (int mf = 0; mf < 4; mf++)
#pragma unroll
        for (int nf = 0; nf < 3; nf++)
          acc[mf][nf] = __builtin_amdgcn_mfma_f32_16x16x32_bf16(a[mf][ks], bfr[nf], acc[mf][nf], 0, 0, 0);
    }

    // write next-l into the other buffer, single barrier per l
    if (il < 7) {
      *(bf16x8*)&Bs[cur ^ 1][(t >> 4) * 136 + (t & 15) * 8] = n0;
      if (t < 80) {
        int c2 = 512 + t;
        *(bf16x8*)&Bs[cur ^ 1][(c2 >> 4) * 136 + (c2 & 15) * 8] = n1;
      }
      __syncthreads();
      cur ^= 1;
    }

    // epilogue (register-only): fuse affine + bias
    float* ob = out2 + (bl * kL + w * 64) * kC;
    const float* afb = affB + bl * kC;
#pragma unroll
    for (int nf = 0; nf < 3; nf++) {
      int c = nf * 16 + fr;
      if (c < kC) {
        float aff = afb[c];
#pragma unroll
        for (int mf = 0; mf < 4; mf++)
          for (int r = 0; r < 4; r++)
            ob[(long)(mf * 16 + hi * 4 + r) * kC + c] = acc[mf][nf][r] + aff;
      }
    }
  }
}

extern "C" void kernel_launch(void* const* d_in, const int* in_sizes, int n_in,
                              void* d_out, int out_size, void* d_ws, size_t ws_size,
                              hipStream_t stream) {
  const float* H        = (const float*)d_in[0];
  const float* W_ah     = (const float*)d_in[1];
  const float* b_ah     = (const float*)d_in[2];
  const float* W_ad     = (const float*)d_in[3];
  const float* b_ad     = (const float*)d_in[4];
  const float* W_arc    = (const float*)d_in[5];
  const float* bias_arc = (const float*)d_in[6];
  const float* W_rh     = (const float*)d_in[7];
  const float* b_rh     = (const float*)d_in[8];
  const float* W_rd     = (const float*)d_in[9];
  const float* b_rd     = (const float*)d_in[10];
  const float* U_rel    = (const float*)d_in[11];
  const float* W_rel    = (const float*)d_in[12];
  const float* bias_rel = (const float*)d_in[13];

  size_t off = 0;
  auto take = [&](size_t nbytes) -> void* {
    void* p = (char*)d_ws + off;
    off += (nbytes + 255) & ~(size_t)255;
    return p;
  };
  short* Hb      = (short*)take(nHB * 2);
  short* Wall    = (short*)take(nWALL * 2);
  float* ballf   = (float*)take(nBALL * 4);
  short* Warcb   = (short*)take(nWARC * 2);
  short* Ut      = (short*)take(nUT * 2);
  short* Proj    = (short*)take((long)kBL * kNP * 2);
  short* T       = (short*)take((long)kBL * kDARC * 2);
  short* Y       = (short*)take((long)kBL * kNY * 2);
  float* rowterm = (float*)take((long)kBL * 4);
  float* affB    = (float*)take((long)kBL * kC * 4);
  if (off > ws_size) return;

  float* outArc = (float*)d_out;
  float* outRel = outArc + (long)kB * kL * kL;

  k_convert<<<dim3(2048), dim3(256), 0, stream>>>(H, W_ah, b_ah, W_ad, b_ad, W_arc,
                                                  W_rh, b_rh, W_rd, b_rd, U_rel,
                                                  Hb, Wall, ballf, Warcb, Ut);
  k_proj<<<dim3(kNP / 128, kBL / 128), dim3(256), 0, stream>>>(Hb, Wall, ballf, Proj);
  k_rowterm<<<dim3(kBL), dim3(64), 0, stream>>>(Proj, bias_arc, rowterm);
  k_affine<<<dim3(kBL), dim3(64), 0, stream>>>(Proj, W_rel, bias_rel, affB);
  k_T<<<dim3(kDARC / 128, kBL / 128), dim3(256), 0, stream>>>(Proj, Warcb, T);
  k_Y<<<dim3(kNY / 128, kBL / 128), dim3(256), 0, stream>>>(Proj, Ut, Y);
  k_sarc<<<dim3(kL / 128, kL / 128, kB), dim3(256), 0, stream>>>(T, Proj, rowterm, outArc);
  k_srel2<<<dim3(kL / 8, kB), dim3(512), 0, stream>>>(Proj, Y, affB, outRel);
}

// Round 4
// 191.264 us; speedup vs baseline: 1.1324x; 1.0495x over previous
//
#include <hip/hip_runtime.h>
#include <hip/hip_bf16.h>

typedef __attribute__((ext_vector_type(8))) short bf16x8;
typedef __attribute__((ext_vector_type(4))) float f32x4;

#define DEVINL __device__ __forceinline__

constexpr int kB = 8, kL = 512, kDH = 768, kDARC = 512, kDREL = 128, kC = 37;
constexpr int kBL = kB * kL;        // 4096
constexpr int kNP = 1280;           // 512+512+128+128 fused projection cols
constexpr int kNY = kC * kDREL;     // 4736

constexpr long nHB   = (long)kBL * kDH;
constexpr long nWALL = (long)kNP * kDH;
constexpr long nWARC = (long)kDARC * kDARC;
constexpr long nUT   = (long)kC * kDREL * kDREL;
constexpr long nBALL = kNP;

DEVINL short f2b(float f) {
  unsigned u = __float_as_uint(f);
  u += 0x7fffu + ((u >> 16) & 1u);   // RNE
  return (short)(u >> 16);
}
DEVINL float b2f(short s) {
  return __uint_as_float(((unsigned)(unsigned short)s) << 16);
}

// async global->LDS, 16B per lane. LDS dest = wave-uniform base + lane*16 (HW).
DEVINL void gload16(const void* g, void* l) {
  __builtin_amdgcn_global_load_lds(
      (const __attribute__((address_space(1))) void*)g,
      (__attribute__((address_space(3))) void*)l, 16, 0, 0);
}

// ---------------- convert / pack inputs to bf16 ----------------
__global__ __launch_bounds__(256) void k_convert(
    const float* __restrict__ H, const float* __restrict__ W_ah, const float* __restrict__ b_ah,
    const float* __restrict__ W_ad, const float* __restrict__ b_ad,
    const float* __restrict__ W_arc, const float* __restrict__ W_rh, const float* __restrict__ b_rh,
    const float* __restrict__ W_rd, const float* __restrict__ b_rd, const float* __restrict__ U,
    short* __restrict__ Hb, short* __restrict__ Wall, float* __restrict__ ballf,
    short* __restrict__ Warcb, short* __restrict__ Ut)
{
  const long total = nHB + nWALL + nWARC + nUT + nBALL;
  for (long i = (long)blockIdx.x * blockDim.x + threadIdx.x; i < total;
       i += (long)gridDim.x * blockDim.x) {
    if (i < nHB) {
      Hb[i] = f2b(H[i]);
    } else if (i < nHB + nWALL) {
      long j = i - nHB; int row = (int)(j / kDH); int k = (int)(j - (long)row * kDH);
      float v;
      if (row < 512)       v = W_ah[(long)row * kDH + k];
      else if (row < 1024) v = W_ad[(long)(row - 512) * kDH + k];
      else if (row < 1152) v = W_rh[(long)(row - 1024) * kDH + k];
      else                 v = W_rd[(long)(row - 1152) * kDH + k];
      Wall[j] = f2b(v);
    } else if (i < nHB + nWALL + nWARC) {
      long j = i - nHB - nWALL;
      Warcb[j] = f2b(W_arc[j]);
    } else if (i < nHB + nWALL + nWARC + nUT) {
      long j = i - nHB - nWALL - nWARC;
      int c = (int)(j >> 14); int rem = (int)(j & 16383); int e = rem >> 7; int d = rem & 127;
      Ut[j] = f2b(U[(long)c * 16384 + (long)d * 128 + e]);   // Ut[c][e][d] = U[c][d][e]
    } else {
      int n = (int)(i - nHB - nWALL - nWARC - nUT);
      float v;
      if (n < 512)       v = b_ah[n];
      else if (n < 1024) v = b_ad[n - 512];
      else if (n < 1152) v = b_rh[n - 1024];
      else               v = b_rd[n - 1152];
      ballf[n] = v;
    }
  }
}

// ---------------- 128x128 core: acc += A[128,K] * B[128,K]^T ----------------
// 256 threads / 4 waves; wave (wm,wn) owns a 64x64 quadrant. BK=64.
DEVINL void gemm128_core(const short* __restrict__ Ag, long lda,
                         const short* __restrict__ Bg, long ldb,
                         int K, f32x4 acc[4][4])
{
  __shared__ short As[128 * 64];
  __shared__ short Bs[128 * 64];
  const int t = threadIdx.x, lane = t & 63, w = t >> 6;
  const int wm = w >> 1, wn = w & 1, fr = lane & 15, hi = lane >> 4;
  const int srow = w * 8 + (lane >> 3);
  const int scol = (lane & 7) * 8;
  const short* Arow = Ag + (long)srow * lda + scol;
  const short* Brow = Bg + (long)srow * ldb + scol;

  for (int k0 = 0; k0 < K; k0 += 64) {
    __syncthreads();
#pragma unroll
    for (int i = 0; i < 4; i++) {
      gload16(Arow + (long)i * 32 * lda + k0, &As[(i * 4 + w) * 512]);
      gload16(Brow + (long)i * 32 * ldb + k0, &Bs[(i * 4 + w) * 512]);
    }
    __syncthreads();
#pragma unroll
    for (int ks = 0; ks < 2; ks++) {
      bf16x8 a[4], b[4];
#pragma unroll
      for (int mf = 0; mf < 4; mf++)
        a[mf] = *(const bf16x8*)&As[(wm * 64 + mf * 16 + fr) * 64 + ks * 32 + hi * 8];
#pragma unroll
      for (int nf = 0; nf < 4; nf++)
        b[nf] = *(const bf16x8*)&Bs[(wn * 64 + nf * 16 + fr) * 64 + ks * 32 + hi * 8];
#pragma unroll
      for (int mf = 0; mf < 4; mf++)
#pragma unroll
        for (int nf = 0; nf < 4; nf++)
          acc[mf][nf] = __builtin_amdgcn_mfma_f32_16x16x32_bf16(a[mf], b[nf], acc[mf][nf], 0, 0, 0);
    }
  }
}

#define ZERO_ACC16 \
  f32x4 acc[4][4]; \
  for (int i = 0; i < 4; i++) for (int j = 0; j < 4; j++) for (int r = 0; r < 4; r++) acc[i][j][r] = 0.f;

// ---------------- projections: Proj = relu(Hb * Wall^T + ballf), bf16 out ----------------
__global__ __launch_bounds__(256) void k_proj(const short* __restrict__ Hb,
    const short* __restrict__ Wall, const float* __restrict__ ballf,
    short* __restrict__ Proj)
{
  const int tn = blockIdx.x, tm = blockIdx.y;
  ZERO_ACC16;
  gemm128_core(Hb + (long)tm * 128 * kDH, kDH, Wall + (long)tn * 128 * kDH, kDH, kDH, acc);
  const int lane = threadIdx.x & 63; const int w = threadIdx.x >> 6;
  const int wm = w >> 1, wn = w & 1, fr = lane & 15, hi = lane >> 4;
  for (int mf = 0; mf < 4; mf++) for (int nf = 0; nf < 4; nf++) for (int r = 0; r < 4; r++) {
    int row = tm * 128 + wm * 64 + mf * 16 + hi * 4 + r;
    int col = tn * 128 + wn * 64 + nf * 16 + fr;
    float v = acc[mf][nf][r] + ballf[col];
    v = v > 0.f ? v : 0.f;
    Proj[(long)row * kNP + col] = f2b(v);
  }
}

// ---------------- k_mid: T-tiles + Y-tiles + (rowterm|affine) in one launch ----------------
// blocks [0,128): T = Had*W_arc^T (4 n-tiles x 32 m-tiles)
// blocks [128,1312): Y = Hrh*Ut^T (37 n-tiles x 32 m-tiles)
// blocks [1312,1824): small path, 8 bl per block (4 waves x 2)
__global__ __launch_bounds__(256) void k_mid(const short* __restrict__ Proj,
    const short* __restrict__ Warcb, const short* __restrict__ Ut,
    const float* __restrict__ bias_arc, const float* __restrict__ W_rel,
    const float* __restrict__ bias_rel,
    short* __restrict__ T, short* __restrict__ Y,
    float* __restrict__ rowterm, float* __restrict__ affB)
{
  const int bx = blockIdx.x;
  const int t = threadIdx.x;
  __shared__ float h[4][256];

  if (bx < 1312) {
    const short* Ag; const short* Bg;
    long lda, ldb, ldd; int K, tm, tn; short* dst;
    if (bx < 128) {
      tn = bx & 3; tm = bx >> 2;
      Ag = Proj + (long)tm * 128 * kNP + 512; lda = kNP;
      Bg = Warcb + (long)tn * 128 * kDARC;    ldb = kDARC;
      K = kDARC; dst = T; ldd = kDARC;
    } else {
      int i = bx - 128; tn = i % 37; tm = i / 37;
      Ag = Proj + (long)tm * 128 * kNP + 1024; lda = kNP;
      Bg = Ut + (long)tn * 128 * kDREL;        ldb = kDREL;
      K = kDREL; dst = Y; ldd = kNY;
    }
    ZERO_ACC16;
    gemm128_core(Ag, lda, Bg, ldb, K, acc);
    const int lane = t & 63; const int w = t >> 6;
    const int wm = w >> 1, wn = w & 1, fr = lane & 15, hi = lane >> 4;
    for (int mf = 0; mf < 4; mf++) for (int nf = 0; nf < 4; nf++) for (int r = 0; r < 4; r++) {
      int row = tm * 128 + wm * 64 + mf * 16 + hi * 4 + r;
      int col = tn * 128 + wn * 64 + nf * 16 + fr;
      dst[(long)row * ldd + col] = f2b(acc[mf][nf][r]);
    }
  } else {
    const int base = (bx - 1312) * 8;
    const int w = t >> 6, lane = t & 63;
    for (int j = 0; j < 2; j++) {
      const int bl = base + w * 2 + j;
      const short* prow = Proj + (long)bl * kNP;
      // rowterm[bl] = Hah[bl,:].bias_arc
      float s = 0.f;
      bf16x8 hv = *(const bf16x8*)(prow + lane * 8);
#pragma unroll
      for (int i = 0; i < 8; i++) s += b2f(hv[i]) * bias_arc[lane * 8 + i];
      for (int off = 32; off; off >>= 1) s += __shfl_down(s, off, 64);
      if (lane == 0) rowterm[bl] = s;
      // affB[bl,c] = concat(Hrh,Hrd)[bl].W_rel[c] + bias_rel[c]
      if (lane < 32) {
        bf16x8 v = *(const bf16x8*)(prow + 1024 + lane * 8);
        for (int i = 0; i < 8; i++) h[w][lane * 8 + i] = b2f(v[i]);
      }
      __syncthreads();
      if (lane < kC) {
        float sa = bias_rel[lane];
        const float* wr = W_rel + (long)lane * 256;
        for (int k = 0; k < 256; k++) sa += h[w][k] * wr[k];
        affB[(long)bl * kC + lane] = sa;
      }
      __syncthreads();
    }
  }
}

// ---------------- k_out: sarc (256x128 tiles) + srel in one 512-thread launch ----------------
// blocks [0,64): S_arc tiles: b=i>>3, tm=(i&7)>>2 (2 x 256 rows), tn=i&3 (4 x 128 cols)
// blocks [64,576): srel: i-64 -> l0=(i&63)*8, b=i>>6
__global__ __launch_bounds__(512) void k_out(const short* __restrict__ T,
    const short* __restrict__ Proj, const float* __restrict__ rowterm,
    const short* __restrict__ Y, const float* __restrict__ affB,
    float* __restrict__ outArc, float* __restrict__ outRel)
{
  __shared__ short sm[24576];   // union: sarc {As 256x64, Bs 128x64} / srel {2 x 48x136}
  const int t = threadIdx.x;
  const int lane = t & 63, w = t >> 6;
  const int fr = lane & 15, hi = lane >> 4;

  if (blockIdx.x < 64) {
    // ---- sarc path ----
    const int i = blockIdx.x;
    const int b = i >> 3, tm = (i >> 2) & 1, tn = i & 3;
    const int wm = w >> 1, wn = w & 1;     // wm 0..3 (64-row quads of 256), wn 0..1
    short* As = sm;                        // 256 x 64
    short* Bs = sm + 16384;                // 128 x 64
    const short* Ag = T + ((long)b * kL + tm * 256) * kDARC;
    const short* Bg = Proj + ((long)b * kL + tn * 128) * kNP;
    const int sr8 = lane >> 3;
    const int sc = (lane & 7) * 8;
    const short* Arow = Ag + (long)(w * 8 + sr8) * kDARC + sc;
    const short* Brow = Bg + (long)(w * 8 + sr8) * kNP + sc;

    ZERO_ACC16;
    for (int k0 = 0; k0 < kDARC; k0 += 64) {
      __syncthreads();
#pragma unroll
      for (int i2 = 0; i2 < 4; i2++)
        gload16(Arow + (long)i2 * 64 * kDARC + k0, &As[(i2 * 64 + w * 8) * 64]);
#pragma unroll
      for (int i2 = 0; i2 < 2; i2++)
        gload16(Brow + (long)i2 * 64 * kNP + k0, &Bs[(i2 * 64 + w * 8) * 64]);
      __syncthreads();
#pragma unroll
      for (int ks = 0; ks < 2; ks++) {
        bf16x8 a[4], bb[4];
#pragma unroll
        for (int mf = 0; mf < 4; mf++)
          a[mf] = *(const bf16x8*)&As[(wm * 64 + mf * 16 + fr) * 64 + ks * 32 + hi * 8];
#pragma unroll
        for (int nf = 0; nf < 4; nf++)
          bb[nf] = *(const bf16x8*)&Bs[(wn * 64 + nf * 16 + fr) * 64 + ks * 32 + hi * 8];
#pragma unroll
        for (int mf = 0; mf < 4; mf++)
#pragma unroll
          for (int nf = 0; nf < 4; nf++)
            acc[mf][nf] = __builtin_amdgcn_mfma_f32_16x16x32_bf16(a[mf], bb[nf], acc[mf][nf], 0, 0, 0);
      }
    }
    for (int mf = 0; mf < 4; mf++) for (int nf = 0; nf < 4; nf++) for (int r = 0; r < 4; r++) {
      int l = tm * 256 + wm * 64 + mf * 16 + hi * 4 + r;
      int m = tn * 128 + wn * 64 + nf * 16 + fr;
      outArc[((long)b * kL + l) * kL + m] = acc[mf][nf][r] + rowterm[(long)b * kL + l];
    }
  } else {
    // ---- srel path ----
    const int i = blockIdx.x - 64;
    const int b = i >> 6;
    const int l0 = (i & 63) * 8;
    short* Bcur = sm;            // 48*136 = 6528 shorts
    short* Bnxt = sm + 6528;

    // zero pad rows 37..47 of both buffers
    if (t < 352) {
      int buf = t / 176, q = t % 176;
      int c = 37 + (q >> 4), e = (q & 15) * 8;
      bf16x8 z = {0, 0, 0, 0, 0, 0, 0, 0};
      *(bf16x8*)&sm[buf * 6528 + c * 136 + e] = z;
    }

    // A fragments: Hrd rows b*512 + w*64 + mf*16 + fr (Proj cols 1152+)
    bf16x8 a[4][4];
    const short* Ab = Proj + ((long)b * kL + w * 64) * kNP + 1152;
#pragma unroll
    for (int mf = 0; mf < 4; mf++)
#pragma unroll
      for (int ks = 0; ks < 4; ks++)
        a[mf][ks] = *(const bf16x8*)(Ab + (long)(mf * 16 + fr) * kNP + ks * 32 + hi * 8);

    // prologue: stage l0 into Bcur
    {
      const short* Yrow = Y + ((long)b * kL + l0) * kNY;
      bf16x8 s0 = *(const bf16x8*)(Yrow + t * 8);
      *(bf16x8*)&Bcur[(t >> 4) * 136 + (t & 15) * 8] = s0;
      if (t < 80) {
        int c2 = 512 + t;
        bf16x8 s1 = *(const bf16x8*)(Yrow + (long)c2 * 8);
        *(bf16x8*)&Bcur[(c2 >> 4) * 136 + (c2 & 15) * 8] = s1;
      }
    }
    __syncthreads();

    for (int il = 0; il < 8; il++) {
      const long bl = (long)b * kL + l0 + il;

      bf16x8 n0, n1;
      if (il < 7) {
        const short* Yn = Y + (bl + 1) * kNY;
        n0 = *(const bf16x8*)(Yn + t * 8);
        if (t < 80) n1 = *(const bf16x8*)(Yn + (long)(512 + t) * 8);
      }

      f32x4 acc[4][3];
#pragma unroll
      for (int mf = 0; mf < 4; mf++)
#pragma unroll
        for (int nf = 0; nf < 3; nf++)
          for (int r = 0; r < 4; r++) acc[mf][nf][r] = 0.f;

#pragma unroll
      for (int ks = 0; ks < 4; ks++) {
        bf16x8 bfr[3];
#pragma unroll
        for (int nf = 0; nf < 3; nf++)
          bfr[nf] = *(const bf16x8*)&Bcur[(nf * 16 + fr) * 136 + ks * 32 + hi * 8];
#pragma unroll
        for (int mf = 0; mf < 4; mf++)
#pragma unroll
          for (int nf = 0; nf < 3; nf++)
            acc[mf][nf] = __builtin_amdgcn_mfma_f32_16x16x32_bf16(a[mf][ks], bfr[nf], acc[mf][nf], 0, 0, 0);
      }

      if (il < 7) {
        *(bf16x8*)&Bnxt[(t >> 4) * 136 + (t & 15) * 8] = n0;
        if (t < 80) {
          int c2 = 512 + t;
          *(bf16x8*)&Bnxt[(c2 >> 4) * 136 + (c2 & 15) * 8] = n1;
        }
        __syncthreads();
        short* tmp = Bcur; Bcur = Bnxt; Bnxt = tmp;
      }

      float* ob = outRel + (bl * kL + w * 64) * kC;
      const float* afb = affB + bl * kC;
#pragma unroll
      for (int nf = 0; nf < 3; nf++) {
        int c = nf * 16 + fr;
        if (c < kC) {
          float aff = afb[c];
#pragma unroll
          for (int mf = 0; mf < 4; mf++)
            for (int r = 0; r < 4; r++)
              ob[(long)(mf * 16 + hi * 4 + r) * kC + c] = acc[mf][nf][r] + aff;
        }
      }
    }
  }
}

extern "C" void kernel_launch(void* const* d_in, const int* in_sizes, int n_in,
                              void* d_out, int out_size, void* d_ws, size_t ws_size,
                              hipStream_t stream) {
  const float* H        = (const float*)d_in[0];
  const float* W_ah     = (const float*)d_in[1];
  const float* b_ah     = (const float*)d_in[2];
  const float* W_ad     = (const float*)d_in[3];
  const float* b_ad     = (const float*)d_in[4];
  const float* W_arc    = (const float*)d_in[5];
  const float* bias_arc = (const float*)d_in[6];
  const float* W_rh     = (const float*)d_in[7];
  const float* b_rh     = (const float*)d_in[8];
  const float* W_rd     = (const float*)d_in[9];
  const float* b_rd     = (const float*)d_in[10];
  const float* U_rel    = (const float*)d_in[11];
  const float* W_rel    = (const float*)d_in[12];
  const float* bias_rel = (const float*)d_in[13];

  size_t off = 0;
  auto take = [&](size_t nbytes) -> void* {
    void* p = (char*)d_ws + off;
    off += (nbytes + 255) & ~(size_t)255;
    return p;
  };
  short* Hb      = (short*)take(nHB * 2);
  short* Wall    = (short*)take(nWALL * 2);
  float* ballf   = (float*)take(nBALL * 4);
  short* Warcb   = (short*)take(nWARC * 2);
  short* Ut      = (short*)take(nUT * 2);
  short* Proj    = (short*)take((long)kBL * kNP * 2);
  short* T       = (short*)take((long)kBL * kDARC * 2);
  short* Y       = (short*)take((long)kBL * kNY * 2);
  float* rowterm = (float*)take((long)kBL * 4);
  float* affB    = (float*)take((long)kBL * kC * 4);
  if (off > ws_size) return;

  float* outArc = (float*)d_out;
  float* outRel = outArc + (long)kB * kL * kL;

  k_convert<<<dim3(2048), dim3(256), 0, stream>>>(H, W_ah, b_ah, W_ad, b_ad, W_arc,
                                                  W_rh, b_rh, W_rd, b_rd, U_rel,
                                                  Hb, Wall, ballf, Warcb, Ut);
  k_proj<<<dim3(kNP / 128, kBL / 128), dim3(256), 0, stream>>>(Hb, Wall, ballf, Proj);
  k_mid<<<dim3(1824), dim3(256), 0, stream>>>(Proj, Warcb, Ut, bias_arc, W_rel, bias_rel,
                                              T, Y, rowterm, affB);
  k_out<<<dim3(576), dim3(512), 0, stream>>>(T, Proj, rowterm, Y, affB, outArc, outRel);
}

// Round 5
// 160.955 us; speedup vs baseline: 1.3456x; 1.1883x over previous
//
#include <hip/hip_runtime.h>
#include <hip/hip_bf16.h>

typedef __attribute__((ext_vector_type(8))) short bf16x8;
typedef __attribute__((ext_vector_type(4))) float f32x4;

#define DEVINL __device__ __forceinline__

constexpr int kB = 8, kL = 512, kDH = 768, kDARC = 512, kDREL = 128, kC = 37;
constexpr int kBL = kB * kL;        // 4096
constexpr int kNP = 1280;           // 512+512+128+128 fused projection cols
constexpr int kNY = kC * kDREL;     // 4736

constexpr long nHB   = (long)kBL * kDH;
constexpr long nWALL = (long)kNP * kDH;
constexpr long nWARC = (long)kDARC * kDARC;
constexpr long nUT   = (long)kC * kDREL * kDREL;
constexpr long nBALL = kNP;

DEVINL short f2b(float f) {
  unsigned u = __float_as_uint(f);
  u += 0x7fffu + ((u >> 16) & 1u);   // RNE
  return (short)(u >> 16);
}
DEVINL float b2f(short s) {
  return __uint_as_float(((unsigned)(unsigned short)s) << 16);
}

// async global->LDS, 16B per lane. LDS dest = wave-uniform base + lane*16 (HW).
DEVINL void gload16(const void* g, void* l) {
  __builtin_amdgcn_global_load_lds(
      (const __attribute__((address_space(1))) void*)g,
      (__attribute__((address_space(3))) void*)l, 16, 0, 0);
}

// ---------------- convert / pack inputs to bf16 ----------------
__global__ __launch_bounds__(256) void k_convert(
    const float* __restrict__ H, const float* __restrict__ W_ah, const float* __restrict__ b_ah,
    const float* __restrict__ W_ad, const float* __restrict__ b_ad,
    const float* __restrict__ W_arc, const float* __restrict__ W_rh, const float* __restrict__ b_rh,
    const float* __restrict__ W_rd, const float* __restrict__ b_rd, const float* __restrict__ U,
    short* __restrict__ Hb, short* __restrict__ Wall, float* __restrict__ ballf,
    short* __restrict__ Warcb, short* __restrict__ Ut)
{
  const long total = nHB + nWALL + nWARC + nUT + nBALL;
  for (long i = (long)blockIdx.x * blockDim.x + threadIdx.x; i < total;
       i += (long)gridDim.x * blockDim.x) {
    if (i < nHB) {
      Hb[i] = f2b(H[i]);
    } else if (i < nHB + nWALL) {
      long j = i - nHB; int row = (int)(j / kDH); int k = (int)(j - (long)row * kDH);
      float v;
      if (row < 512)       v = W_ah[(long)row * kDH + k];
      else if (row < 1024) v = W_ad[(long)(row - 512) * kDH + k];
      else if (row < 1152) v = W_rh[(long)(row - 1024) * kDH + k];
      else                 v = W_rd[(long)(row - 1152) * kDH + k];
      Wall[j] = f2b(v);
    } else if (i < nHB + nWALL + nWARC) {
      long j = i - nHB - nWALL;
      Warcb[j] = f2b(W_arc[j]);
    } else if (i < nHB + nWALL + nWARC + nUT) {
      long j = i - nHB - nWALL - nWARC;
      int c = (int)(j >> 14); int rem = (int)(j & 16383); int e = rem >> 7; int d = rem & 127;
      Ut[j] = f2b(U[(long)c * 16384 + (long)d * 128 + e]);   // Ut[c][e][d] = U[c][d][e]
    } else {
      int n = (int)(i - nHB - nWALL - nWARC - nUT);
      float v;
      if (n < 512)       v = b_ah[n];
      else if (n < 1024) v = b_ad[n - 512];
      else if (n < 1152) v = b_rh[n - 1024];
      else               v = b_rd[n - 1152];
      ballf[n] = v;
    }
  }
}

// ---------------- 128x128 core: acc += A[128,K] * B[128,K]^T ----------------
// 256 threads / 4 waves; wave (wm,wn) owns a 64x64 quadrant. BK=64.
// As/Bs: 128*64 shorts each, caller-provided LDS.
DEVINL void gemm128_core(short* As, short* Bs,
                         const short* __restrict__ Ag, long lda,
                         const short* __restrict__ Bg, long ldb,
                         int K, f32x4 acc[4][4])
{
  const int t = threadIdx.x, lane = t & 63, w = t >> 6;
  const int wm = w >> 1, wn = w & 1, fr = lane & 15, hi = lane >> 4;
  const int srow = w * 8 + (lane >> 3);
  const int scol = (lane & 7) * 8;
  const short* Arow = Ag + (long)srow * lda + scol;
  const short* Brow = Bg + (long)srow * ldb + scol;

  for (int k0 = 0; k0 < K; k0 += 64) {
    __syncthreads();
#pragma unroll
    for (int i = 0; i < 4; i++) {
      gload16(Arow + (long)i * 32 * lda + k0, &As[(i * 4 + w) * 512]);
      gload16(Brow + (long)i * 32 * ldb + k0, &Bs[(i * 4 + w) * 512]);
    }
    __syncthreads();
#pragma unroll
    for (int ks = 0; ks < 2; ks++) {
      bf16x8 a[4], b[4];
#pragma unroll
      for (int mf = 0; mf < 4; mf++)
        a[mf] = *(const bf16x8*)&As[(wm * 64 + mf * 16 + fr) * 64 + ks * 32 + hi * 8];
#pragma unroll
      for (int nf = 0; nf < 4; nf++)
        b[nf] = *(const bf16x8*)&Bs[(wn * 64 + nf * 16 + fr) * 64 + ks * 32 + hi * 8];
#pragma unroll
      for (int mf = 0; mf < 4; mf++)
#pragma unroll
        for (int nf = 0; nf < 4; nf++)
          acc[mf][nf] = __builtin_amdgcn_mfma_f32_16x16x32_bf16(a[mf], b[nf], acc[mf][nf], 0, 0, 0);
    }
  }
}

#define ZERO_ACC16 \
  f32x4 acc[4][4]; \
  for (int i = 0; i < 4; i++) for (int j = 0; j < 4; j++) for (int r = 0; r < 4; r++) acc[i][j][r] = 0.f;

// ---------------- projections: Proj = relu(Hb * Wall^T + ballf), bf16 out ----------------
__global__ __launch_bounds__(256) void k_proj(const short* __restrict__ Hb,
    const short* __restrict__ Wall, const float* __restrict__ ballf,
    short* __restrict__ Proj)
{
  __shared__ short As[128 * 64], Bs[128 * 64];
  const int tn = blockIdx.x, tm = blockIdx.y;
  ZERO_ACC16;
  gemm128_core(As, Bs, Hb + (long)tm * 128 * kDH, kDH, Wall + (long)tn * 128 * kDH, kDH, kDH, acc);
  const int lane = threadIdx.x & 63; const int w = threadIdx.x >> 6;
  const int wm = w >> 1, wn = w & 1, fr = lane & 15, hi = lane >> 4;
  for (int mf = 0; mf < 4; mf++) for (int nf = 0; nf < 4; nf++) for (int r = 0; r < 4; r++) {
    int row = tm * 128 + wm * 64 + mf * 16 + hi * 4 + r;
    int col = tn * 128 + wn * 64 + nf * 16 + fr;
    float v = acc[mf][nf][r] + ballf[col];
    v = v > 0.f ? v : 0.f;
    Proj[(long)row * kNP + col] = f2b(v);
  }
}

// ---------------- k_mid: T-tiles + Y-tiles + (rowterm|affine) in one launch ----------------
__global__ __launch_bounds__(256) void k_mid(const short* __restrict__ Proj,
    const short* __restrict__ Warcb, const short* __restrict__ Ut,
    const float* __restrict__ bias_arc, const float* __restrict__ W_rel,
    const float* __restrict__ bias_rel,
    short* __restrict__ T, short* __restrict__ Y,
    float* __restrict__ rowterm, float* __restrict__ affB)
{
  __shared__ short As[128 * 64], Bs[128 * 64];
  const int bx = blockIdx.x;
  const int t = threadIdx.x;

  if (bx < 1312) {
    const short* Ag; const short* Bg;
    long lda, ldb, ldd; int K, tm, tn; short* dst;
    if (bx < 128) {
      tn = bx & 3; tm = bx >> 2;
      Ag = Proj + (long)tm * 128 * kNP + 512; lda = kNP;
      Bg = Warcb + (long)tn * 128 * kDARC;    ldb = kDARC;
      K = kDARC; dst = T; ldd = kDARC;
    } else {
      int i = bx - 128; tn = i % 37; tm = i / 37;
      Ag = Proj + (long)tm * 128 * kNP + 1024; lda = kNP;
      Bg = Ut + (long)tn * 128 * kDREL;        ldb = kDREL;
      K = kDREL; dst = Y; ldd = kNY;
    }
    ZERO_ACC16;
    gemm128_core(As, Bs, Ag, lda, Bg, ldb, K, acc);
    const int lane = t & 63; const int w = t >> 6;
    const int wm = w >> 1, wn = w & 1, fr = lane & 15, hi = lane >> 4;
    for (int mf = 0; mf < 4; mf++) for (int nf = 0; nf < 4; nf++) for (int r = 0; r < 4; r++) {
      int row = tm * 128 + wm * 64 + mf * 16 + hi * 4 + r;
      int col = tn * 128 + wn * 64 + nf * 16 + fr;
      dst[(long)row * ldd + col] = f2b(acc[mf][nf][r]);
    }
  } else {
    __shared__ float h[4][256];
    const int base = (bx - 1312) * 8;
    const int w = t >> 6, lane = t & 63;
    for (int j = 0; j < 2; j++) {
      const int bl = base + w * 2 + j;
      const short* prow = Proj + (long)bl * kNP;
      float s = 0.f;
      bf16x8 hv = *(const bf16x8*)(prow + lane * 8);
#pragma unroll
      for (int i = 0; i < 8; i++) s += b2f(hv[i]) * bias_arc[lane * 8 + i];
      for (int off = 32; off; off >>= 1) s += __shfl_down(s, off, 64);
      if (lane == 0) rowterm[bl] = s;
      if (lane < 32) {
        bf16x8 v = *(const bf16x8*)(prow + 1024 + lane * 8);
        for (int i = 0; i < 8; i++) h[w][lane * 8 + i] = b2f(v[i]);
      }
      __syncthreads();
      if (lane < kC) {
        float sa = bias_rel[lane];
        const float* wr = W_rel + (long)lane * 256;
        for (int k = 0; k < 256; k++) sa += h[w][k] * wr[k];
        affB[(long)bl * kC + lane] = sa;
      }
      __syncthreads();
    }
  }
}

// ---------------- k_out: sarc (128x128 tiles) + srel v3, 256 threads, dyn LDS ----------------
// blocks [0,128): S_arc: b=i>>4, tm=(i>>2)&3, tn=i&3
// blocks [128,1152): srel: idx=i-128: h=idx&1 (m-half), lc=(idx>>1)&63, b=idx>>7
__global__ __launch_bounds__(256) void k_out(const short* __restrict__ T,
    const short* __restrict__ Proj, const float* __restrict__ rowterm,
    const short* __restrict__ Y, const float* __restrict__ affB,
    float* __restrict__ outArc, float* __restrict__ outRel)
{
  extern __shared__ short sm[];   // 32768 B: sarc {As,Bs 128x64} / srel {2 x 48x136 + scratch}
  const int t = threadIdx.x;
  const int lane = t & 63, w = t >> 6;
  const int fr = lane & 15, hi = lane >> 4;

  if (blockIdx.x < 128) {
    // ---- sarc: S_arc[b, tm*128.., tn*128..] = T_b Hah_b^T + rowterm ----
    const int i = blockIdx.x;
    const int b = i >> 4, tm = (i >> 2) & 3, tn = i & 3;
    ZERO_ACC16;
    gemm128_core(sm, sm + 8192,
                 T + ((long)b * kL + tm * 128) * kDARC, kDARC,
                 Proj + ((long)b * kL + tn * 128) * kNP, kNP, kDARC, acc);
    const int wm = w >> 1, wn = w & 1;
    for (int mf = 0; mf < 4; mf++) for (int nf = 0; nf < 4; nf++) for (int r = 0; r < 4; r++) {
      int l = tm * 128 + wm * 64 + mf * 16 + hi * 4 + r;
      int m = tn * 128 + wn * 64 + nf * 16 + fr;
      outArc[((long)b * kL + l) * kL + m] = acc[mf][nf][r] + rowterm[(long)b * kL + l];
    }
  } else {
    // ---- srel v3: 4 waves cover 256 m-rows (half h); coalesced stores via LDS transpose ----
    const int idx = blockIdx.x - 128;
    const int h = idx & 1;
    const int l0 = ((idx >> 1) & 63) * 8;
    const int b = idx >> 7;
    const int mbase = h * 256;
    short* Bcur = sm;            // 48*136 = 6528 shorts = 13056 B
    short* Bnxt = sm + 6528;

    // A fragments: Hrd rows b*512 + mbase + w*64 + mf*16 + fr (Proj cols 1152+)
    bf16x8 a[4][4];
    const short* Ab = Proj + ((long)b * kL + mbase + w * 64) * kNP + 1152;
#pragma unroll
    for (int mf = 0; mf < 4; mf++)
#pragma unroll
      for (int ks = 0; ks < 4; ks++)
        a[mf][ks] = *(const bf16x8*)(Ab + (long)(mf * 16 + fr) * kNP + ks * 32 + hi * 8);

    // prologue: stage Y[l0] into Bcur (592 bf16x8 chunks over 256 threads)
    {
      const short* Yrow = Y + ((long)b * kL + l0) * kNY;
#pragma unroll
      for (int p = 0; p < 3; p++) {
        int i2 = p * 256 + t;
        if (i2 < 592)
          *(bf16x8*)&Bcur[(i2 >> 4) * 136 + (i2 & 15) * 8] = *(const bf16x8*)(Yrow + i2 * 8);
      }
    }
    __syncthreads();

    for (int il = 0; il < 8; il++) {
      const long bl = (long)b * kL + l0 + il;

      // T14: issue next-l global loads before compute
      bf16x8 n0, n1, n2;
      if (il < 7) {
        const short* Yn = Y + (bl + 1) * kNY;
        n0 = *(const bf16x8*)(Yn + t * 8);
        n1 = *(const bf16x8*)(Yn + (long)(256 + t) * 8);
        if (t < 80) n2 = *(const bf16x8*)(Yn + (long)(512 + t) * 8);
      }

      f32x4 acc[4][3];
#pragma unroll
      for (int mf = 0; mf < 4; mf++)
#pragma unroll
        for (int nf = 0; nf < 3; nf++)
          for (int r = 0; r < 4; r++) acc[mf][nf][r] = 0.f;

#pragma unroll
      for (int ks = 0; ks < 4; ks++) {
        bf16x8 bfr[3];
#pragma unroll
        for (int nf = 0; nf < 3; nf++)
          bfr[nf] = *(const bf16x8*)&Bcur[(nf * 16 + fr) * 136 + ks * 32 + hi * 8];
#pragma unroll
        for (int mf = 0; mf < 4; mf++)
#pragma unroll
          for (int nf = 0; nf < 3; nf++)
            acc[mf][nf] = __builtin_amdgcn_mfma_f32_16x16x32_bf16(a[mf][ks], bfr[nf], acc[mf][nf], 0, 0, 0);
      }
      __syncthreads();   // all waves done reading Bcur; its space becomes scratch

      // fused affine values for this l
      float aff[3];
#pragma unroll
      for (int nf = 0; nf < 3; nf++) {
        int c = nf * 16 + fr;
        aff[nf] = (c < kC) ? affB[bl * kC + c] : 0.f;
      }

      // epilogue: per (wave, mf) transpose 16x37 through per-wave scratch in Bcur,
      // then 148 dwordx4 coalesced stores.
      float* scr = (float*)Bcur + w * 592;   // 592 f32 = 2368 B per wave slice
#pragma unroll
      for (int mf = 0; mf < 4; mf++) {
#pragma unroll
        for (int nf = 0; nf < 3; nf++) {
          int c = nf * 16 + fr;
          if (c < kC) {
#pragma unroll
            for (int r = 0; r < 4; r++)
              scr[(hi * 4 + r) * kC + c] = acc[mf][nf][r] + aff[nf];
          }
        }
        // wave-internal RAW on LDS: compiler inserts lgkmcnt
        float* gb = outRel + (bl * kL + mbase + w * 64 + mf * 16) * kC;
#pragma unroll
        for (int p = 0; p < 3; p++) {
          int i4 = p * 64 + lane;
          if (i4 < 148) {
            f32x4 v = *(f32x4*)&scr[i4 * 4];
            *(f32x4*)&gb[i4 * 4] = v;
          }
        }
      }

      if (il < 7) {
        *(bf16x8*)&Bnxt[(t >> 4) * 136 + (t & 15) * 8] = n0;
        {
          int i2 = 256 + t;
          *(bf16x8*)&Bnxt[(i2 >> 4) * 136 + (i2 & 15) * 8] = n1;
        }
        if (t < 80) {
          int i2 = 512 + t;
          *(bf16x8*)&Bnxt[(i2 >> 4) * 136 + (i2 & 15) * 8] = n2;
        }
        __syncthreads();
        short* tmp = Bcur; Bcur = Bnxt; Bnxt = tmp;
      }
    }
  }
}

extern "C" void kernel_launch(void* const* d_in, const int* in_sizes, int n_in,
                              void* d_out, int out_size, void* d_ws, size_t ws_size,
                              hipStream_t stream) {
  const float* H        = (const float*)d_in[0];
  const float* W_ah     = (const float*)d_in[1];
  const float* b_ah     = (const float*)d_in[2];
  const float* W_ad     = (const float*)d_in[3];
  const float* b_ad     = (const float*)d_in[4];
  const float* W_arc    = (const float*)d_in[5];
  const float* bias_arc = (const float*)d_in[6];
  const float* W_rh     = (const float*)d_in[7];
  const float* b_rh     = (const float*)d_in[8];
  const float* W_rd     = (const float*)d_in[9];
  const float* b_rd     = (const float*)d_in[10];
  const float* U_rel    = (const float*)d_in[11];
  const float* W_rel    = (const float*)d_in[12];
  const float* bias_rel = (const float*)d_in[13];

  size_t off = 0;
  auto take = [&](size_t nbytes) -> void* {
    void* p = (char*)d_ws + off;
    off += (nbytes + 255) & ~(size_t)255;
    return p;
  };
  short* Hb      = (short*)take(nHB * 2);
  short* Wall    = (short*)take(nWALL * 2);
  float* ballf   = (float*)take(nBALL * 4);
  short* Warcb   = (short*)take(nWARC * 2);
  short* Ut      = (short*)take(nUT * 2);
  short* Proj    = (short*)take((long)kBL * kNP * 2);
  short* T       = (short*)take((long)kBL * kDARC * 2);
  short* Y       = (short*)take((long)kBL * kNY * 2);
  float* rowterm = (float*)take((long)kBL * 4);
  float* affB    = (float*)take((long)kBL * kC * 4);
  if (off > ws_size) return;

  float* outArc = (float*)d_out;
  float* outRel = outArc + (long)kB * kL * kL;

  k_convert<<<dim3(2048), dim3(256), 0, stream>>>(H, W_ah, b_ah, W_ad, b_ad, W_arc,
                                                  W_rh, b_rh, W_rd, b_rd, U_rel,
                                                  Hb, Wall, ballf, Warcb, Ut);
  k_proj<<<dim3(kNP / 128, kBL / 128), dim3(256), 0, stream>>>(Hb, Wall, ballf, Proj);
  k_mid<<<dim3(1824), dim3(256), 0, stream>>>(Proj, Warcb, Ut, bias_arc, W_rel, bias_rel,
                                              T, Y, rowterm, affB);
  k_out<<<dim3(1152), dim3(256), 32768, stream>>>(T, Proj, rowterm, Y, affB, outArc, outRel);
}